// Round 1
// baseline (9238.056 us; speedup 1.0000x reference)
//
#include <hip/hip_runtime.h>

#define T_STEPS 2048
#define BATCH   64
#define IN_DIM  256
#define HID     512

typedef _Float16 half_t;
typedef half_t half2_t __attribute__((ext_vector_type(2)));

#if __has_builtin(__builtin_amdgcn_fdot2)
__device__ __forceinline__ float fdot2(half2_t a, half2_t b, float c) {
    return __builtin_amdgcn_fdot2(a, b, c, false);   // v_dot2_f32_f16
}
#else
__device__ __forceinline__ float fdot2(half2_t a, half2_t b, float c) {
    return c + (float)a.x * (float)b.x + (float)a.y * (float)b.y;
}
#endif

// 16B bundle of 4 half2 pairs (trivially copyable -> ds_read_b128)
struct alignas(16) h2x4 { half2_t a, b, c, d; };

// ---------------------------------------------------------------------------
// K1: x_proj[t*B+b][h] = input[t*B+b][i] @ w_in[i][h]   (unchanged)
// ---------------------------------------------------------------------------
__global__ __launch_bounds__(256, 4)
void xproj_gemm(const float* __restrict__ A, const float* __restrict__ Win,
                float* __restrict__ out) {
    __shared__ float As[32][132];
    __shared__ float Bs[32][132];
    const int tid = threadIdx.x;
    const int m0 = blockIdx.y * 128;
    const int n0 = blockIdx.x * 128;
    const int tm = (tid >> 4) << 3;
    const int tn = (tid & 15) << 3;

    float acc[8][8] = {};

    for (int k0 = 0; k0 < IN_DIM; k0 += 32) {
        {
            const int m  = tid >> 3;
            const int k4 = (tid & 7) << 2;
#pragma unroll
            for (int r = 0; r < 4; ++r) {
                const float4 a4 = *(const float4*)&A[(size_t)(m0 + m + 32 * r) * IN_DIM + k0 + k4];
                As[k4 + 0][m + 32 * r] = a4.x;
                As[k4 + 1][m + 32 * r] = a4.y;
                As[k4 + 2][m + 32 * r] = a4.z;
                As[k4 + 3][m + 32 * r] = a4.w;
            }
        }
        {
            const int kb = tid >> 5;
            const int n4 = (tid & 31) << 2;
#pragma unroll
            for (int r = 0; r < 4; ++r) {
                const float4 b4 = *(const float4*)&Win[(size_t)(k0 + kb + 8 * r) * HID + n0 + n4];
                *(float4*)&Bs[kb + 8 * r][n4] = b4;
            }
        }
        __syncthreads();
#pragma unroll
        for (int kk = 0; kk < 32; ++kk) {
            const float4 a0 = *(const float4*)&As[kk][tm];
            const float4 a1 = *(const float4*)&As[kk][tm + 4];
            const float4 b0 = *(const float4*)&Bs[kk][tn];
            const float4 b1 = *(const float4*)&Bs[kk][tn + 4];
            const float av[8] = {a0.x, a0.y, a0.z, a0.w, a1.x, a1.y, a1.z, a1.w};
            const float bv[8] = {b0.x, b0.y, b0.z, b0.w, b1.x, b1.y, b1.z, b1.w};
#pragma unroll
            for (int i = 0; i < 8; ++i)
#pragma unroll
                for (int j = 0; j < 8; ++j)
                    acc[i][j] = fmaf(av[i], bv[j], acc[i][j]);
        }
        __syncthreads();
    }

#pragma unroll
    for (int i = 0; i < 8; ++i) {
        float4 c0 = {acc[i][0], acc[i][1], acc[i][2], acc[i][3]};
        float4 c1 = {acc[i][4], acc[i][5], acc[i][6], acc[i][7]};
        float* dst = &out[(size_t)(m0 + tm + i) * HID + n0 + tn];
        *(float4*)dst       = c0;
        *(float4*)(dst + 4) = c1;
    }
}

// ---------------------------------------------------------------------------
// K2: sequential scan. 64 WGs (1/batch row), 1024 threads = 16 waves
// (4 waves/SIMD -> hard 128-VGPR cap, no AGPR/scratch round-trips).
// Thread (jg=tid&127, kg=tid>>7) owns cols [4*jg,4*jg+4) x k-rows
// [64*kg, 64*kg+64): 24 k-pairs/col in VGPRs (96 regs), 8 k-pairs/col in a
// 128KB LDS slab read as ds_read_b128. h kept as f16 pairs; each wave's kg is
// uniform so h chunk reads are 16B broadcasts. Partials: parts[8][512],
// conflict-free b128 writes / b32 reads. 2 barriers/step. fp32 accumulation.
// ---------------------------------------------------------------------------
__global__ __launch_bounds__(1024)
void rnn_scan(const float* __restrict__ Wrec, float* __restrict__ out) {
    __shared__ h2x4  WL4[8 * 1024];    // 128 KB: slot s=2*c+q, addr s*1024+tid
    __shared__ float parts[8][512];    // 16 KB
    __shared__ h2x4  h4buf[64];        // 1 KB: current h as 512 f16

    const int tid   = threadIdx.x;
    const int b     = blockIdx.x;
    const int jg    = tid & 127;
    const int kg    = tid >> 7;          // uniform per wave (wave w -> kg = w>>1)
    const int col0  = jg << 2;           // 4 cols
    const int kbase = kg << 6;           // 64 k-rows

    // ---- load W: regs (k-pairs 0..23) + LDS (k-pairs 24..31)
    half2_t wreg[4][24];
#pragma unroll
    for (int p = 0; p < 24; ++p) {
        const int k = kbase + 2 * p;
        const float4 lo = *(const float4*)&Wrec[(size_t)k * HID + col0];
        const float4 hi = *(const float4*)&Wrec[(size_t)(k + 1) * HID + col0];
        wreg[0][p].x = (half_t)lo.x; wreg[0][p].y = (half_t)hi.x;
        wreg[1][p].x = (half_t)lo.y; wreg[1][p].y = (half_t)hi.y;
        wreg[2][p].x = (half_t)lo.z; wreg[2][p].y = (half_t)hi.z;
        wreg[3][p].x = (half_t)lo.w; wreg[3][p].y = (half_t)hi.w;
    }
#pragma unroll
    for (int q = 0; q < 2; ++q) {
        half2_t t0[4], t1[4], t2[4], t3[4];   // [pp] for cols 0..3
#pragma unroll
        for (int pp = 0; pp < 4; ++pp) {
            const int k = kbase + 2 * (24 + 4 * q + pp);
            const float4 lo = *(const float4*)&Wrec[(size_t)k * HID + col0];
            const float4 hi = *(const float4*)&Wrec[(size_t)(k + 1) * HID + col0];
            t0[pp].x = (half_t)lo.x; t0[pp].y = (half_t)hi.x;
            t1[pp].x = (half_t)lo.y; t1[pp].y = (half_t)hi.y;
            t2[pp].x = (half_t)lo.z; t2[pp].y = (half_t)hi.z;
            t3[pp].x = (half_t)lo.w; t3[pp].y = (half_t)hi.w;
        }
        h2x4 u;
        u.a = t0[0]; u.b = t0[1]; u.c = t0[2]; u.d = t0[3]; WL4[(0 * 2 + q) * 1024 + tid] = u;
        u.a = t1[0]; u.b = t1[1]; u.c = t1[2]; u.d = t1[3]; WL4[(1 * 2 + q) * 1024 + tid] = u;
        u.a = t2[0]; u.b = t2[1]; u.c = t2[2]; u.d = t2[3]; WL4[(2 * 2 + q) * 1024 + tid] = u;
        u.a = t3[0]; u.b = t3[1]; u.c = t3[2]; u.d = t3[3]; WL4[(3 * 2 + q) * 1024 + tid] = u;
    }
    // h0 = 0
    if (tid < 64) {
        h2x4 z;
        z.a = half2_t{(half_t)0.f, (half_t)0.f}; z.b = z.a; z.c = z.a; z.d = z.a;
        h4buf[tid] = z;
    }
    __syncthreads();

    const int jcol = tid;   // finalize column (valid for tid < 512)
    const h2x4* hbase = &h4buf[kg << 3];

    for (int t = 0; t < T_STEPS; ++t) {
        // prefetch xp (consumed only after the barrier; stays in flight)
        float xpv = 0.f;
        if (tid < HID)
            xpv = out[((size_t)t * BATCH + b) * HID + jcol];

        float acc0 = 0.f, acc1 = 0.f, acc2 = 0.f, acc3 = 0.f;

        // register part: k-pairs 0..23 (h chunks j=0..5, 16B uniform broadcasts)
#pragma unroll
        for (int j = 0; j < 6; ++j) {
            const h2x4 hu = hbase[j];
            acc0 = fdot2(wreg[0][4 * j + 0], hu.a, acc0);
            acc1 = fdot2(wreg[1][4 * j + 0], hu.a, acc1);
            acc2 = fdot2(wreg[2][4 * j + 0], hu.a, acc2);
            acc3 = fdot2(wreg[3][4 * j + 0], hu.a, acc3);
            acc0 = fdot2(wreg[0][4 * j + 1], hu.b, acc0);
            acc1 = fdot2(wreg[1][4 * j + 1], hu.b, acc1);
            acc2 = fdot2(wreg[2][4 * j + 1], hu.b, acc2);
            acc3 = fdot2(wreg[3][4 * j + 1], hu.b, acc3);
            acc0 = fdot2(wreg[0][4 * j + 2], hu.c, acc0);
            acc1 = fdot2(wreg[1][4 * j + 2], hu.c, acc1);
            acc2 = fdot2(wreg[2][4 * j + 2], hu.c, acc2);
            acc3 = fdot2(wreg[3][4 * j + 2], hu.c, acc3);
            acc0 = fdot2(wreg[0][4 * j + 3], hu.d, acc0);
            acc1 = fdot2(wreg[1][4 * j + 3], hu.d, acc1);
            acc2 = fdot2(wreg[2][4 * j + 3], hu.d, acc2);
            acc3 = fdot2(wreg[3][4 * j + 3], hu.d, acc3);
        }
        // LDS part: k-pairs 24..31 (h chunks j=6,7; W via ds_read_b128)
#pragma unroll
        for (int q = 0; q < 2; ++q) {
            const h2x4 hu = hbase[6 + q];
            {
                const h2x4 wu = WL4[(0 * 2 + q) * 1024 + tid];
                acc0 = fdot2(wu.a, hu.a, acc0);
                acc0 = fdot2(wu.b, hu.b, acc0);
                acc0 = fdot2(wu.c, hu.c, acc0);
                acc0 = fdot2(wu.d, hu.d, acc0);
            }
            {
                const h2x4 wu = WL4[(1 * 2 + q) * 1024 + tid];
                acc1 = fdot2(wu.a, hu.a, acc1);
                acc1 = fdot2(wu.b, hu.b, acc1);
                acc1 = fdot2(wu.c, hu.c, acc1);
                acc1 = fdot2(wu.d, hu.d, acc1);
            }
            {
                const h2x4 wu = WL4[(2 * 2 + q) * 1024 + tid];
                acc2 = fdot2(wu.a, hu.a, acc2);
                acc2 = fdot2(wu.b, hu.b, acc2);
                acc2 = fdot2(wu.c, hu.c, acc2);
                acc2 = fdot2(wu.d, hu.d, acc2);
            }
            {
                const h2x4 wu = WL4[(3 * 2 + q) * 1024 + tid];
                acc3 = fdot2(wu.a, hu.a, acc3);
                acc3 = fdot2(wu.b, hu.b, acc3);
                acc3 = fdot2(wu.c, hu.c, acc3);
                acc3 = fdot2(wu.d, hu.d, acc3);
            }
        }
        *(float4*)&parts[kg][col0] = float4{acc0, acc1, acc2, acc3};
        __syncthreads();

        // finalize column jcol: sum 8 partials, add xp, tanh
        if (tid < HID) {
            float s = xpv;
#pragma unroll
            for (int g = 0; g < 8; ++g)
                s += parts[g][jcol];
            const float e  = __expf(2.0f * s);
            const float hj = 1.0f - 2.0f / (e + 1.0f);   // tanh(s), saturates correctly

            out[((size_t)t * BATCH + b) * HID + jcol] = hj;
            if (t == T_STEPS - 1)
                out[(size_t)T_STEPS * BATCH * HID + (size_t)b * HID + jcol] = hj;

            ((half_t*)h4buf)[jcol] = (half_t)hj;
        }
        __syncthreads();
    }
}

extern "C" void kernel_launch(void* const* d_in, const int* in_sizes, int n_in,
                              void* d_out, int out_size, void* d_ws, size_t ws_size,
                              hipStream_t stream) {
    const float* A    = (const float*)d_in[0];   // [T,B,I]
    const float* Win  = (const float*)d_in[1];   // [I,H]
    const float* Wrec = (const float*)d_in[2];   // [H,H]
    float* out = (float*)d_out;                  // [T,B,H] hiddens ++ [B,H] h_last

    dim3 g1(HID / 128, (T_STEPS * BATCH) / 128); // (4, 1024)
    xproj_gemm<<<g1, 256, 0, stream>>>(A, Win, out);
    rnn_scan<<<BATCH, 1024, 0, stream>>>(Wrec, out);
}

// Round 2
// 3626.062 us; speedup vs baseline: 2.5477x; 2.5477x over previous
//
#include <hip/hip_runtime.h>

#define T_STEPS 2048
#define BATCH   64
#define IN_DIM  256
#define HID     512

typedef _Float16 half_t;
typedef half_t half2_t __attribute__((ext_vector_type(2)));

#if __has_builtin(__builtin_amdgcn_fdot2)
__device__ __forceinline__ float fdot2(half2_t a, half2_t b, float c) {
    return __builtin_amdgcn_fdot2(a, b, c, false);   // v_dot2_f32_f16
}
#else
__device__ __forceinline__ float fdot2(half2_t a, half2_t b, float c) {
    return c + (float)a.x * (float)b.x + (float)a.y * (float)b.y;
}
#endif

// 16B bundle of 4 half2 pairs -> ds_read_b128 / ds_write_b128.
// All element accesses use compile-time indices (stays in registers).
struct alignas(16) h2x4 { half2_t v[4]; };

// ---------------------------------------------------------------------------
// K1: x_proj[t*B+b][h] = input[t*B+b][i] @ w_in[i][h]   (unchanged)
// ---------------------------------------------------------------------------
__global__ __launch_bounds__(256, 4)
void xproj_gemm(const float* __restrict__ A, const float* __restrict__ Win,
                float* __restrict__ out) {
    __shared__ float As[32][132];
    __shared__ float Bs[32][132];
    const int tid = threadIdx.x;
    const int m0 = blockIdx.y * 128;
    const int n0 = blockIdx.x * 128;
    const int tm = (tid >> 4) << 3;
    const int tn = (tid & 15) << 3;

    float acc[8][8] = {};

    for (int k0 = 0; k0 < IN_DIM; k0 += 32) {
        {
            const int m  = tid >> 3;
            const int k4 = (tid & 7) << 2;
#pragma unroll
            for (int r = 0; r < 4; ++r) {
                const float4 a4 = *(const float4*)&A[(size_t)(m0 + m + 32 * r) * IN_DIM + k0 + k4];
                As[k4 + 0][m + 32 * r] = a4.x;
                As[k4 + 1][m + 32 * r] = a4.y;
                As[k4 + 2][m + 32 * r] = a4.z;
                As[k4 + 3][m + 32 * r] = a4.w;
            }
        }
        {
            const int kb = tid >> 5;
            const int n4 = (tid & 31) << 2;
#pragma unroll
            for (int r = 0; r < 4; ++r) {
                const float4 b4 = *(const float4*)&Win[(size_t)(k0 + kb + 8 * r) * HID + n0 + n4];
                *(float4*)&Bs[kb + 8 * r][n4] = b4;
            }
        }
        __syncthreads();
#pragma unroll
        for (int kk = 0; kk < 32; ++kk) {
            const float4 a0 = *(const float4*)&As[kk][tm];
            const float4 a1 = *(const float4*)&As[kk][tm + 4];
            const float4 b0 = *(const float4*)&Bs[kk][tn];
            const float4 b1 = *(const float4*)&Bs[kk][tn + 4];
            const float av[8] = {a0.x, a0.y, a0.z, a0.w, a1.x, a1.y, a1.z, a1.w};
            const float bv[8] = {b0.x, b0.y, b0.z, b0.w, b1.x, b1.y, b1.z, b1.w};
#pragma unroll
            for (int i = 0; i < 8; ++i)
#pragma unroll
                for (int j = 0; j < 8; ++j)
                    acc[i][j] = fmaf(av[i], bv[j], acc[i][j]);
        }
        __syncthreads();
    }

#pragma unroll
    for (int i = 0; i < 8; ++i) {
        float4 c0 = {acc[i][0], acc[i][1], acc[i][2], acc[i][3]};
        float4 c1 = {acc[i][4], acc[i][5], acc[i][6], acc[i][7]};
        float* dst = &out[(size_t)(m0 + tm + i) * HID + n0 + tn];
        *(float4*)dst       = c0;
        *(float4*)(dst + 4) = c1;
    }
}

// ---------------------------------------------------------------------------
// K2: sequential scan. 64 WGs (1/batch row), 512 threads = 8 waves.
// LDS (145 KB) pins 1 WG/CU, so occupancy-driven register limiting is pure
// loss: amdgpu_waves_per_eu(2,2) pins the allocator's target at exactly
// 2 waves/EU -> 256-VGPR budget -> wreg (192 half2) lives in arch VGPRs
// (rounds 0/1 showed the default target spilled it to AGPR/scratch:
// VGPR_Count 128/64 = half the budget).
// Thread (jg=tid&63, kg=tid>>6) owns cols [8jg,8jg+8) x k-rows [64kg,64kg+64):
// 24 k-pairs/col in VGPRs, 8 k-pairs/col in a 128KB LDS slab packed as 16B
// bundles ([slot][tid] -> conflict-free ds_read_b128, 16/thread/step).
// h as h2x4 chunks: 8 uniform 16B broadcast reads/thread/step (was 32 b32).
// Partials through skewed LDS (9*jg+c, <=2-way). 2 barriers/step. fp32 acc.
// ---------------------------------------------------------------------------
__global__ __attribute__((amdgpu_flat_work_group_size(512, 512),
                          amdgpu_waves_per_eu(2, 2)))
void rnn_scan(const float* __restrict__ Wrec, float* __restrict__ out) {
    __shared__ h2x4  WL4[16 * 512];    // 128 KB: slot s=c*2+q, addr s*512+tid
    __shared__ float parts[8 * 640];   // 20 KB: [kg][9*jg + c] skewed
    __shared__ h2x4  h4buf[64];        // 1 KB: current h as 512 f16

    const int tid   = threadIdx.x;
    const int b     = blockIdx.x;
    const int jg    = tid & 63;
    const int kg    = tid >> 6;          // == wave id (uniform per wave)
    const int col0  = jg << 3;           // 8 cols
    const int kbase = kg << 6;           // 64 k-rows

    // ---- load W: regs (k-pairs 0..23) + LDS bundles (k-pairs 24..31)
    half2_t wreg[8][24];
#pragma unroll
    for (int p = 0; p < 24; ++p) {
        const int k = kbase + 2 * p;
        const float4 lo0 = *(const float4*)&Wrec[(size_t)k * HID + col0];
        const float4 lo1 = *(const float4*)&Wrec[(size_t)k * HID + col0 + 4];
        const float4 hi0 = *(const float4*)&Wrec[(size_t)(k + 1) * HID + col0];
        const float4 hi1 = *(const float4*)&Wrec[(size_t)(k + 1) * HID + col0 + 4];
        wreg[0][p].x = (half_t)lo0.x; wreg[0][p].y = (half_t)hi0.x;
        wreg[1][p].x = (half_t)lo0.y; wreg[1][p].y = (half_t)hi0.y;
        wreg[2][p].x = (half_t)lo0.z; wreg[2][p].y = (half_t)hi0.z;
        wreg[3][p].x = (half_t)lo0.w; wreg[3][p].y = (half_t)hi0.w;
        wreg[4][p].x = (half_t)lo1.x; wreg[4][p].y = (half_t)hi1.x;
        wreg[5][p].x = (half_t)lo1.y; wreg[5][p].y = (half_t)hi1.y;
        wreg[6][p].x = (half_t)lo1.z; wreg[6][p].y = (half_t)hi1.z;
        wreg[7][p].x = (half_t)lo1.w; wreg[7][p].y = (half_t)hi1.w;
    }
#pragma unroll
    for (int q = 0; q < 2; ++q) {
        h2x4 bu[8];                       // per-col bundle, cols col0..col0+7
#pragma unroll
        for (int pp = 0; pp < 4; ++pp) {
            const int k = kbase + 48 + 8 * q + 2 * pp;   // pair P = 24+4q+pp
            const float4 lo0 = *(const float4*)&Wrec[(size_t)k * HID + col0];
            const float4 lo1 = *(const float4*)&Wrec[(size_t)k * HID + col0 + 4];
            const float4 hi0 = *(const float4*)&Wrec[(size_t)(k + 1) * HID + col0];
            const float4 hi1 = *(const float4*)&Wrec[(size_t)(k + 1) * HID + col0 + 4];
            bu[0].v[pp].x = (half_t)lo0.x; bu[0].v[pp].y = (half_t)hi0.x;
            bu[1].v[pp].x = (half_t)lo0.y; bu[1].v[pp].y = (half_t)hi0.y;
            bu[2].v[pp].x = (half_t)lo0.z; bu[2].v[pp].y = (half_t)hi0.z;
            bu[3].v[pp].x = (half_t)lo0.w; bu[3].v[pp].y = (half_t)hi0.w;
            bu[4].v[pp].x = (half_t)lo1.x; bu[4].v[pp].y = (half_t)hi1.x;
            bu[5].v[pp].x = (half_t)lo1.y; bu[5].v[pp].y = (half_t)hi1.y;
            bu[6].v[pp].x = (half_t)lo1.z; bu[6].v[pp].y = (half_t)hi1.z;
            bu[7].v[pp].x = (half_t)lo1.w; bu[7].v[pp].y = (half_t)hi1.w;
        }
#pragma unroll
        for (int c = 0; c < 8; ++c)
            WL4[(c * 2 + q) * 512 + tid] = bu[c];
    }
    // h0 = 0
    if (tid < 64) {
        h2x4 z;
        z.v[0] = half2_t{(half_t)0.f, (half_t)0.f};
        z.v[1] = z.v[0]; z.v[2] = z.v[0]; z.v[3] = z.v[0];
        h4buf[tid] = z;
    }
    __syncthreads();

    const int jcol  = tid;                       // finalize column
    const int pbase = 9 * (jcol >> 3) + (jcol & 7);
    const h2x4* hbase = &h4buf[kg << 3];         // this wave's 8 h-chunks

    for (int t = 0; t < T_STEPS; ++t) {
        // prefetch xp (used only at finalize; stays in flight across the dots)
        const float xpv = out[((size_t)t * BATCH + b) * HID + jcol];

        float acc[8] = {};

        // register part: k-pairs 0..23 (h chunks j=0..5, uniform 16B broadcasts)
#pragma unroll
        for (int j = 0; j < 6; ++j) {
            const h2x4 hu = hbase[j];
#pragma unroll
            for (int pp = 0; pp < 4; ++pp)
#pragma unroll
                for (int c = 0; c < 8; ++c)
                    acc[c] = fdot2(wreg[c][4 * j + pp], hu.v[pp], acc[c]);
        }
        // LDS part: k-pairs 24..31 (h chunks j=6,7; W via ds_read_b128)
#pragma unroll
        for (int q = 0; q < 2; ++q) {
            const h2x4 hu = hbase[6 + q];
#pragma unroll
            for (int c = 0; c < 8; ++c) {
                const h2x4 wu = WL4[(c * 2 + q) * 512 + tid];
#pragma unroll
                for (int pp = 0; pp < 4; ++pp)
                    acc[c] = fdot2(wu.v[pp], hu.v[pp], acc[c]);
            }
        }
#pragma unroll
        for (int c = 0; c < 8; ++c)
            parts[kg * 640 + 9 * jg + c] = acc[c];
        __syncthreads();

        // finalize column jcol: sum 8 partials, add xp, tanh
        float s = xpv;
#pragma unroll
        for (int g = 0; g < 8; ++g)
            s += parts[g * 640 + pbase];
        const float e  = __expf(2.0f * s);
        const float hj = 1.0f - 2.0f / (e + 1.0f);     // tanh(s), saturates correctly

        out[((size_t)t * BATCH + b) * HID + jcol] = hj;
        if (t == T_STEPS - 1)
            out[(size_t)T_STEPS * BATCH * HID + (size_t)b * HID + jcol] = hj;

        ((half_t*)h4buf)[jcol] = (half_t)hj;
        __syncthreads();
    }
}

extern "C" void kernel_launch(void* const* d_in, const int* in_sizes, int n_in,
                              void* d_out, int out_size, void* d_ws, size_t ws_size,
                              hipStream_t stream) {
    const float* A    = (const float*)d_in[0];   // [T,B,I]
    const float* Win  = (const float*)d_in[1];   // [I,H]
    const float* Wrec = (const float*)d_in[2];   // [H,H]
    float* out = (float*)d_out;                  // [T,B,H] hiddens ++ [B,H] h_last

    dim3 g1(HID / 128, (T_STEPS * BATCH) / 128); // (4, 1024)
    xproj_gemm<<<g1, 256, 0, stream>>>(A, Win, out);
    rnn_scan<<<BATCH, 512, 0, stream>>>(Wrec, out);
}